// Round 3
// baseline (292.192 us; speedup 1.0000x reference)
//
#include <hip/hip_runtime.h>

typedef unsigned short u16;
typedef __attribute__((ext_vector_type(8))) __bf16 bf16x8;
typedef __attribute__((ext_vector_type(4))) float f32x4;

__device__ __forceinline__ u16 f2bf(float f) {
    union { float f; unsigned u; } v; v.f = f;
    unsigned u = v.u;
    u += 0x7FFFu + ((u >> 16) & 1u);
    return (u16)(u >> 16);
}

// ---------------- cast fp32 -> bf16 (vectorized x4) ----------------
__global__ void cast_f32_to_bf16(const float* __restrict__ in, u16* __restrict__ out, int n4) {
    int i = blockIdx.x * 256 + threadIdx.x;
    if (i < n4) {
        float4 f = reinterpret_cast<const float4*>(in)[i];
        ushort4 o;
        o.x = f2bf(f.x); o.y = f2bf(f.y); o.z = f2bf(f.z); o.w = f2bf(f.w);
        reinterpret_cast<ushort4*>(out)[i] = o;
    }
}

// ---------------- QKV projection GEMM ----------------
// A = xb [8192][768] bf16, Bm = wb [2304][768] bf16 (Wq|Wk|Wv rows, K-contig)
// out: q,k as [B,H,N,D] bf16 (q scaled by 0.125), v transposed as [B,H,D,N] bf16
__global__ __launch_bounds__(256, 2) void gemm_qkv(
    const u16* __restrict__ A, const u16* __restrict__ Bm,
    u16* __restrict__ qo, u16* __restrict__ ko, u16* __restrict__ vto)
{
    __shared__ u16 As[128][40];
    __shared__ u16 Bs[128][40];
    const int tid = threadIdx.x;
    const int wave = tid >> 6, lane = tid & 63;
    const int quad = lane >> 4, l16 = lane & 15;
    const int wr = (wave >> 1) * 64, wc = (wave & 1) * 64;
    const int rowBase = blockIdx.y * 128;
    const int colBase = blockIdx.x * 128;

    f32x4 acc[4][4] = {};

    const int r0 = tid >> 2;
    const int c0 = (tid & 3) * 8;
    const u16* ap = A + (size_t)(rowBase + r0) * 768 + c0;
    const u16* bp2 = Bm + (size_t)(colBase + r0) * 768 + c0;

    for (int k0 = 0; k0 < 768; k0 += 32) {
        __syncthreads();
        *reinterpret_cast<int4*>(&As[r0][c0])      = *reinterpret_cast<const int4*>(ap + k0);
        *reinterpret_cast<int4*>(&As[r0 + 64][c0]) = *reinterpret_cast<const int4*>(ap + 64 * 768 + k0);
        *reinterpret_cast<int4*>(&Bs[r0][c0])      = *reinterpret_cast<const int4*>(bp2 + k0);
        *reinterpret_cast<int4*>(&Bs[r0 + 64][c0]) = *reinterpret_cast<const int4*>(bp2 + 64 * 768 + k0);
        __syncthreads();
        bf16x8 a[4], b[4];
        #pragma unroll
        for (int mi = 0; mi < 4; mi++)
            a[mi] = *reinterpret_cast<const bf16x8*>(&As[wr + mi * 16 + l16][quad * 8]);
        #pragma unroll
        for (int ni = 0; ni < 4; ni++)
            b[ni] = *reinterpret_cast<const bf16x8*>(&Bs[wc + ni * 16 + l16][quad * 8]);
        #pragma unroll
        for (int mi = 0; mi < 4; mi++)
            #pragma unroll
            for (int ni = 0; ni < 4; ni++)
                acc[mi][ni] = __builtin_amdgcn_mfma_f32_16x16x32_bf16(a[mi], b[ni], acc[mi][ni], 0, 0, 0);
    }

    #pragma unroll
    for (int mi = 0; mi < 4; mi++) {
        #pragma unroll
        for (int ni = 0; ni < 4; ni++) {
            int gj = colBase + wc + ni * 16 + l16;     // 0..2303
            int which = gj / 768;                      // 0=q,1=k,2=v (uniform per tile)
            int r = gj - which * 768;
            int h = r >> 6, d = r & 63;
            int gi0 = rowBase + wr + mi * 16 + quad * 4;
            int b_ = gi0 >> 10;                        // constant across 4 rows (gi0 % 4 == 0)
            int n0 = gi0 & 1023;
            if (which == 2) {
                // v transposed: 4 consecutive n at fixed d -> one 8B store
                ushort4 pk;
                pk.x = f2bf(acc[mi][ni][0]);
                pk.y = f2bf(acc[mi][ni][1]);
                pk.z = f2bf(acc[mi][ni][2]);
                pk.w = f2bf(acc[mi][ni][3]);
                *reinterpret_cast<ushort4*>(vto + ((size_t)(b_ * 12 + h) * 64 + d) * 1024 + n0) = pk;
            } else {
                float s = (which == 0) ? 0.125f : 1.0f;
                u16* dst = (which == 0 ? qo : ko) + ((size_t)(b_ * 12 + h) * 1024 + n0) * 64 + d;
                #pragma unroll
                for (int rr = 0; rr < 4; rr++)
                    dst[(size_t)rr * 64] = f2bf(acc[mi][ni][rr] * s);
            }
        }
    }
}

// ---------------- fused flash attention (v3: XCD swizzle + reg prefetch) ----------------
// q,k: [B,H,N,D] bf16 (q pre-scaled), vt: [B,H,D,N] bf16, ao: [B,N,H*D] bf16
// S^T = K*Q^T (query on l16): per-lane row sums, packed b64 P stores, zero barriers.
// K frags register-double-buffered (prefetch chunk j+1 during chunk j);
// V frags issued at chunk start, consumed after softmax (latency covered).
// Grid (bh, qt): same-head q-tiles land on same XCD -> K/V served from L2.
__device__ __forceinline__ void load_k_frags(
    int j, const u16* kb, int quad, int l16, bf16x8 kf[2][4])
{
    #pragma unroll
    for (int ks = 0; ks < 2; ks++)
        #pragma unroll
        for (int mi = 0; mi < 4; mi++)
            kf[ks][mi] = *reinterpret_cast<const bf16x8*>(
                kb + (size_t)(j + mi * 16 + l16) * 64 + ks * 32 + quad * 8);
}

__device__ __forceinline__ void attn_chunk(
    int j0, int jn, bool pf_ok,
    const u16* kb, const u16* vb,
    bf16x8 kf[2][4], bf16x8 kfn[2][4],
    const bf16x8 qf[2][2],
    f32x4 o[2][4], float lsum[2],
    u16 (*PsW)[72], int quad, int l16)
{
    // V for current chunk: issued now, first used after softmax
    bf16x8 vf[2][4];
    #pragma unroll
    for (int ks = 0; ks < 2; ks++)
        #pragma unroll
        for (int di = 0; di < 4; di++)
            vf[ks][di] = *reinterpret_cast<const bf16x8*>(
                vb + (size_t)(di * 16 + l16) * 1024 + j0 + ks * 32 + quad * 8);

    // prefetch next chunk's K into the other register buffer
    if (pf_ok) load_k_frags(jn, kb, quad, l16, kfn);

    // S^T = K @ Q^T : C rows = keys (quad*4+reg), C cols = queries (l16)
    f32x4 s[4][2] = {};
    #pragma unroll
    for (int ks = 0; ks < 2; ks++)
        #pragma unroll
        for (int mi = 0; mi < 4; mi++)
            #pragma unroll
            for (int ni = 0; ni < 2; ni++)
                s[mi][ni] = __builtin_amdgcn_mfma_f32_16x16x32_bf16(kf[ks][mi], qf[ni][ks], s[mi][ni], 0, 0, 0);

    // exp (no max-subtract; scores bounded ~|2|), per-lane l accum, packed P store
    #pragma unroll
    for (int mi = 0; mi < 4; mi++) {
        #pragma unroll
        for (int ni = 0; ni < 2; ni++) {
            float p0 = __expf(s[mi][ni][0]);
            float p1 = __expf(s[mi][ni][1]);
            float p2 = __expf(s[mi][ni][2]);
            float p3 = __expf(s[mi][ni][3]);
            lsum[ni] += (p0 + p1) + (p2 + p3);
            ushort4 pk;
            pk.x = f2bf(p0); pk.y = f2bf(p1); pk.z = f2bf(p2); pk.w = f2bf(p3);
            *reinterpret_cast<ushort4*>(&PsW[ni * 16 + l16][mi * 16 + quad * 4]) = pk;
        }
    }

    // O += P @ V (P from wave-private LDS rows, V from regs)
    #pragma unroll
    for (int ks = 0; ks < 2; ks++) {
        bf16x8 pf[2];
        #pragma unroll
        for (int mi = 0; mi < 2; mi++)
            pf[mi] = *reinterpret_cast<const bf16x8*>(&PsW[mi * 16 + l16][ks * 32 + quad * 8]);
        #pragma unroll
        for (int mi = 0; mi < 2; mi++)
            #pragma unroll
            for (int di = 0; di < 4; di++)
                o[mi][di] = __builtin_amdgcn_mfma_f32_16x16x32_bf16(pf[mi], vf[ks][di], o[mi][di], 0, 0, 0);
    }
}

__global__ __launch_bounds__(256, 3) void attn_fwd(
    const u16* __restrict__ q, const u16* __restrict__ k,
    const u16* __restrict__ vt, u16* __restrict__ ao)
{
    __shared__ u16 Ps[128][72];
    const int bh = blockIdx.x, qt = blockIdx.y;   // bh fast => same head -> same XCD (96%8==0)
    const int b = bh / 12, h = bh - b * 12;
    const int tid = threadIdx.x;
    const int wave = tid >> 6, lane = tid & 63;
    const int quad = lane >> 4, l16 = lane & 15;
    u16 (*PsW)[72] = &Ps[wave * 32];

    const u16* qb = q + (size_t)bh * 65536 + ((size_t)qt * 128 + wave * 32) * 64;
    const u16* kb = k + (size_t)bh * 65536;
    const u16* vb = vt + (size_t)bh * 65536;

    // Q frags (B-operand of S^T): lane l16 = query row, k-dim = ks*32+quad*8
    bf16x8 qf[2][2];
    #pragma unroll
    for (int ni = 0; ni < 2; ni++)
        #pragma unroll
        for (int ks = 0; ks < 2; ks++)
            qf[ni][ks] = *reinterpret_cast<const bf16x8*>(qb + (ni * 16 + l16) * 64 + ks * 32 + quad * 8);

    f32x4 o[2][4] = {};              // [query tile][d tile]
    float lsum[2] = {0.f, 0.f};      // per-lane partial row sums (query = ni*16+l16)

    bf16x8 kf[2][2][4];              // double-buffered K fragments
    load_k_frags(0, kb, quad, l16, kf[0]);

    for (int j0 = 0; j0 < 1024; j0 += 128) {
        attn_chunk(j0,      j0 + 64,  true,             kb, vb, kf[0], kf[1], qf, o, lsum, PsW, quad, l16);
        attn_chunk(j0 + 64, j0 + 128, j0 + 128 < 1024,  kb, vb, kf[1], kf[0], qf, o, lsum, PsW, quad, l16);
    }

    // finalize l: reduce across quads (value for query ni*16+l16, replicated)
    #pragma unroll
    for (int ni = 0; ni < 2; ni++) {
        lsum[ni] += __shfl_xor(lsum[ni], 16, 64);
        lsum[ni] += __shfl_xor(lsum[ni], 32, 64);
    }

    // epilogue: O rows are queries (quad*4+r); fetch that row's l via shfl(width 16)
    #pragma unroll
    for (int mi = 0; mi < 2; mi++) {
        #pragma unroll
        for (int r = 0; r < 4; r++) {
            float lv = __shfl(lsum[mi], quad * 4 + r, 16);
            float inv = 1.0f / lv;
            int n = qt * 128 + wave * 32 + mi * 16 + quad * 4 + r;
            size_t base = (size_t)(b * 1024 + n) * 768 + h * 64;
            #pragma unroll
            for (int di = 0; di < 4; di++)
                ao[base + di * 16 + l16] = f2bf(o[mi][di][r] * inv);
        }
    }
}

// ---------------- output projection GEMM (+bias, fp32 out) ----------------
__global__ __launch_bounds__(256, 2) void gemm_proj(
    const u16* __restrict__ A, const u16* __restrict__ Bm,
    const float* __restrict__ bias, float* __restrict__ out)
{
    __shared__ u16 As[128][40];
    __shared__ u16 Bs[128][40];
    const int tid = threadIdx.x;
    const int wave = tid >> 6, lane = tid & 63;
    const int quad = lane >> 4, l16 = lane & 15;
    const int wr = (wave >> 1) * 64, wc = (wave & 1) * 64;
    const int rowBase = blockIdx.y * 128;
    const int colBase = blockIdx.x * 128;

    f32x4 acc[4][4] = {};

    const int r0 = tid >> 2;
    const int c0 = (tid & 3) * 8;
    const u16* ap = A + (size_t)(rowBase + r0) * 768 + c0;
    const u16* bp2 = Bm + (size_t)(colBase + r0) * 768 + c0;

    for (int k0 = 0; k0 < 768; k0 += 32) {
        __syncthreads();
        *reinterpret_cast<int4*>(&As[r0][c0])      = *reinterpret_cast<const int4*>(ap + k0);
        *reinterpret_cast<int4*>(&As[r0 + 64][c0]) = *reinterpret_cast<const int4*>(ap + 64 * 768 + k0);
        *reinterpret_cast<int4*>(&Bs[r0][c0])      = *reinterpret_cast<const int4*>(bp2 + k0);
        *reinterpret_cast<int4*>(&Bs[r0 + 64][c0]) = *reinterpret_cast<const int4*>(bp2 + 64 * 768 + k0);
        __syncthreads();
        bf16x8 a[4], b[4];
        #pragma unroll
        for (int mi = 0; mi < 4; mi++)
            a[mi] = *reinterpret_cast<const bf16x8*>(&As[wr + mi * 16 + l16][quad * 8]);
        #pragma unroll
        for (int ni = 0; ni < 4; ni++)
            b[ni] = *reinterpret_cast<const bf16x8*>(&Bs[wc + ni * 16 + l16][quad * 8]);
        #pragma unroll
        for (int mi = 0; mi < 4; mi++)
            #pragma unroll
            for (int ni = 0; ni < 4; ni++)
                acc[mi][ni] = __builtin_amdgcn_mfma_f32_16x16x32_bf16(a[mi], b[ni], acc[mi][ni], 0, 0, 0);
    }

    #pragma unroll
    for (int mi = 0; mi < 4; mi++) {
        #pragma unroll
        for (int ni = 0; ni < 4; ni++) {
            int gj = colBase + wc + ni * 16 + l16;
            float bv = bias[gj];
            int gi0 = rowBase + wr + mi * 16 + quad * 4;
            #pragma unroll
            for (int rr2 = 0; rr2 < 4; rr2++)
                out[(size_t)(gi0 + rr2) * 768 + gj] = acc[mi][ni][rr2] + bv;
        }
    }
}

extern "C" void kernel_launch(void* const* d_in, const int* in_sizes, int n_in,
                              void* d_out, int out_size, void* d_ws, size_t ws_size,
                              hipStream_t stream) {
    const float* x  = (const float*)d_in[0];
    const float* Wq = (const float*)d_in[1];
    const float* Wk = (const float*)d_in[2];
    const float* Wv = (const float*)d_in[3];
    const float* Wp = (const float*)d_in[4];
    const float* bp = (const float*)d_in[5];
    float* out = (float*)d_out;

    // workspace layout (bf16 elements); total ~64.5 MB
    u16* xb  = (u16*)d_ws;            // 6291456  : x as bf16 [8192][768]
    u16* wb  = xb  + 6291456;         // 1769472  : Wq|Wk|Wv [2304][768]
    u16* wpb = wb  + 1769472;         // 589824   : Wp [768][768]
    u16* qo  = wpb + 589824;          // 6291456  : q [B,H,N,D] (scaled)
    u16* ko  = qo  + 6291456;         // 6291456  : k [B,H,N,D]
    u16* vto = ko  + 6291456;         // 6291456  : v^T [B,H,D,N]
    u16* ao  = vto + 6291456;         // 6291456  : attn out [B,N,H*D]

    cast_f32_to_bf16<<<6144, 256, 0, stream>>>(x,  xb,  1572864);
    cast_f32_to_bf16<<<576,  256, 0, stream>>>(Wq, wb,            147456);
    cast_f32_to_bf16<<<576,  256, 0, stream>>>(Wk, wb + 589824,   147456);
    cast_f32_to_bf16<<<576,  256, 0, stream>>>(Wv, wb + 1179648,  147456);
    cast_f32_to_bf16<<<576,  256, 0, stream>>>(Wp, wpb,           147456);

    gemm_qkv<<<dim3(18, 64), 256, 0, stream>>>(xb, wb, qo, ko, vto);
    attn_fwd<<<dim3(96, 8), 256, 0, stream>>>(qo, ko, vto, ao);
    gemm_proj<<<dim3(6, 64), 256, 0, stream>>>(ao, wpb, bp, out);
}

// Round 4
// 258.794 us; speedup vs baseline: 1.1291x; 1.1291x over previous
//
#include <hip/hip_runtime.h>

typedef unsigned short u16;
typedef __attribute__((ext_vector_type(8))) __bf16 bf16x8;
typedef __attribute__((ext_vector_type(4))) float f32x4;

__device__ __forceinline__ u16 f2bf(float f) {
    union { float f; unsigned u; } v; v.f = f;
    unsigned u = v.u;
    u += 0x7FFFu + ((u >> 16) & 1u);
    return (u16)(u >> 16);
}

// ---------------- cast fp32 -> bf16 (vectorized x4) ----------------
__global__ void cast_f32_to_bf16(const float* __restrict__ in, u16* __restrict__ out, int n4) {
    int i = blockIdx.x * 256 + threadIdx.x;
    if (i < n4) {
        float4 f = reinterpret_cast<const float4*>(in)[i];
        ushort4 o;
        o.x = f2bf(f.x); o.y = f2bf(f.y); o.z = f2bf(f.z); o.w = f2bf(f.w);
        reinterpret_cast<ushort4*>(out)[i] = o;
    }
}

// ---------------- QKV projection GEMM ----------------
// A = xb [8192][768] bf16, Bm = wb [2304][768] bf16 (Wq|Wk|Wv rows, K-contig)
// out: q,k as [B,H,N,D] bf16 (q scaled by 0.125), v transposed as [B,H,D,N] bf16
__global__ __launch_bounds__(256, 2) void gemm_qkv(
    const u16* __restrict__ A, const u16* __restrict__ Bm,
    u16* __restrict__ qo, u16* __restrict__ ko, u16* __restrict__ vto)
{
    __shared__ u16 As[128][40];
    __shared__ u16 Bs[128][40];
    const int tid = threadIdx.x;
    const int wave = tid >> 6, lane = tid & 63;
    const int quad = lane >> 4, l16 = lane & 15;
    const int wr = (wave >> 1) * 64, wc = (wave & 1) * 64;
    const int rowBase = blockIdx.y * 128;
    const int colBase = blockIdx.x * 128;

    f32x4 acc[4][4] = {};

    const int r0 = tid >> 2;
    const int c0 = (tid & 3) * 8;
    const u16* ap = A + (size_t)(rowBase + r0) * 768 + c0;
    const u16* bp2 = Bm + (size_t)(colBase + r0) * 768 + c0;

    for (int k0 = 0; k0 < 768; k0 += 32) {
        __syncthreads();
        *reinterpret_cast<int4*>(&As[r0][c0])      = *reinterpret_cast<const int4*>(ap + k0);
        *reinterpret_cast<int4*>(&As[r0 + 64][c0]) = *reinterpret_cast<const int4*>(ap + 64 * 768 + k0);
        *reinterpret_cast<int4*>(&Bs[r0][c0])      = *reinterpret_cast<const int4*>(bp2 + k0);
        *reinterpret_cast<int4*>(&Bs[r0 + 64][c0]) = *reinterpret_cast<const int4*>(bp2 + 64 * 768 + k0);
        __syncthreads();
        bf16x8 a[4], b[4];
        #pragma unroll
        for (int mi = 0; mi < 4; mi++)
            a[mi] = *reinterpret_cast<const bf16x8*>(&As[wr + mi * 16 + l16][quad * 8]);
        #pragma unroll
        for (int ni = 0; ni < 4; ni++)
            b[ni] = *reinterpret_cast<const bf16x8*>(&Bs[wc + ni * 16 + l16][quad * 8]);
        #pragma unroll
        for (int mi = 0; mi < 4; mi++)
            #pragma unroll
            for (int ni = 0; ni < 4; ni++)
                acc[mi][ni] = __builtin_amdgcn_mfma_f32_16x16x32_bf16(a[mi], b[ni], acc[mi][ni], 0, 0, 0);
    }

    #pragma unroll
    for (int mi = 0; mi < 4; mi++) {
        #pragma unroll
        for (int ni = 0; ni < 4; ni++) {
            int gj = colBase + wc + ni * 16 + l16;     // 0..2303
            int which = gj / 768;                      // 0=q,1=k,2=v (uniform per tile)
            int r = gj - which * 768;
            int h = r >> 6, d = r & 63;
            int gi0 = rowBase + wr + mi * 16 + quad * 4;
            int b_ = gi0 >> 10;                        // constant across 4 rows (gi0 % 4 == 0)
            int n0 = gi0 & 1023;
            if (which == 2) {
                // v transposed: 4 consecutive n at fixed d -> one 8B store
                ushort4 pk;
                pk.x = f2bf(acc[mi][ni][0]);
                pk.y = f2bf(acc[mi][ni][1]);
                pk.z = f2bf(acc[mi][ni][2]);
                pk.w = f2bf(acc[mi][ni][3]);
                *reinterpret_cast<ushort4*>(vto + ((size_t)(b_ * 12 + h) * 64 + d) * 1024 + n0) = pk;
            } else {
                float s = (which == 0) ? 0.125f : 1.0f;
                u16* dst = (which == 0 ? qo : ko) + ((size_t)(b_ * 12 + h) * 1024 + n0) * 64 + d;
                #pragma unroll
                for (int rr = 0; rr < 4; rr++)
                    dst[(size_t)rr * 64] = f2bf(acc[mi][ni][rr] * s);
            }
        }
    }
}

// ---------------- fused flash attention (v4: XCD swizzle, K-then-V issue order,
// NO register double-buffer -- v3's kf[2][..] prefetch spilled ~170MB to scratch) ----------------
// q,k: [B,H,N,D] bf16 (q pre-scaled), vt: [B,H,D,N] bf16, ao: [B,N,H*D] bf16
// S^T = K*Q^T (query on l16): per-lane row sums, packed b64 P stores, zero barriers.
// Per chunk: issue 8 K loads, then 8 V loads. S-MFMA drains only K (vmcnt(8),
// FIFO), so V latency hides under S-MFMA + softmax. Grid (bh, qt): all q-tiles
// of a head land on one XCD -> K/V served from its L2 (FETCH 104->48 MB, R3).
__global__ __launch_bounds__(256, 3) void attn_fwd(
    const u16* __restrict__ q, const u16* __restrict__ k,
    const u16* __restrict__ vt, u16* __restrict__ ao)
{
    __shared__ u16 Ps[128][72];
    const int bh = blockIdx.x, qt = blockIdx.y;   // bh fast => same head -> same XCD (96%8==0)
    const int b = bh / 12, h = bh - b * 12;
    const int tid = threadIdx.x;
    const int wave = tid >> 6, lane = tid & 63;
    const int quad = lane >> 4, l16 = lane & 15;
    u16 (*PsW)[72] = &Ps[wave * 32];

    const u16* qb = q + (size_t)bh * 65536 + ((size_t)qt * 128 + wave * 32) * 64;
    const u16* kb = k + (size_t)bh * 65536;
    const u16* vb = vt + (size_t)bh * 65536;

    // Q frags (B-operand of S^T): lane l16 = query row, k-dim = ks*32+quad*8
    bf16x8 qf[2][2];
    #pragma unroll
    for (int ni = 0; ni < 2; ni++)
        #pragma unroll
        for (int ks = 0; ks < 2; ks++)
            qf[ni][ks] = *reinterpret_cast<const bf16x8*>(qb + (ni * 16 + l16) * 64 + ks * 32 + quad * 8);

    f32x4 o[2][4] = {};              // [query tile][d tile]
    float lsum[2] = {0.f, 0.f};      // per-lane partial row sums (query = ni*16+l16)

    for (int j0 = 0; j0 < 1024; j0 += 64) {
        // K loads first (oldest in FIFO -> consumable at vmcnt(8))
        bf16x8 kf[2][4];
        #pragma unroll
        for (int ks = 0; ks < 2; ks++)
            #pragma unroll
            for (int mi = 0; mi < 4; mi++)
                kf[ks][mi] = *reinterpret_cast<const bf16x8*>(
                    kb + (size_t)(j0 + mi * 16 + l16) * 64 + ks * 32 + quad * 8);
        // V loads second: stay in flight through S-MFMA + softmax
        bf16x8 vf[2][4];
        #pragma unroll
        for (int ks = 0; ks < 2; ks++)
            #pragma unroll
            for (int di = 0; di < 4; di++)
                vf[ks][di] = *reinterpret_cast<const bf16x8*>(
                    vb + (size_t)(di * 16 + l16) * 1024 + j0 + ks * 32 + quad * 8);

        // S^T = K @ Q^T : C rows = keys (quad*4+reg), C cols = queries (l16)
        f32x4 s[4][2] = {};
        #pragma unroll
        for (int ks = 0; ks < 2; ks++)
            #pragma unroll
            for (int mi = 0; mi < 4; mi++)
                #pragma unroll
                for (int ni = 0; ni < 2; ni++)
                    s[mi][ni] = __builtin_amdgcn_mfma_f32_16x16x32_bf16(kf[ks][mi], qf[ni][ks], s[mi][ni], 0, 0, 0);

        // exp (no max-subtract; scores bounded ~|2|), per-lane l accum, packed P store
        #pragma unroll
        for (int mi = 0; mi < 4; mi++) {
            #pragma unroll
            for (int ni = 0; ni < 2; ni++) {
                float p0 = __expf(s[mi][ni][0]);
                float p1 = __expf(s[mi][ni][1]);
                float p2 = __expf(s[mi][ni][2]);
                float p3 = __expf(s[mi][ni][3]);
                lsum[ni] += (p0 + p1) + (p2 + p3);
                ushort4 pk;
                pk.x = f2bf(p0); pk.y = f2bf(p1); pk.z = f2bf(p2); pk.w = f2bf(p3);
                *reinterpret_cast<ushort4*>(&PsW[ni * 16 + l16][mi * 16 + quad * 4]) = pk;
            }
        }

        // O += P @ V (P from wave-private LDS rows, V from regs)
        #pragma unroll
        for (int ks = 0; ks < 2; ks++) {
            bf16x8 pf[2];
            #pragma unroll
            for (int mi = 0; mi < 2; mi++)
                pf[mi] = *reinterpret_cast<const bf16x8*>(&PsW[mi * 16 + l16][ks * 32 + quad * 8]);
            #pragma unroll
            for (int mi = 0; mi < 2; mi++)
                #pragma unroll
                for (int di = 0; di < 4; di++)
                    o[mi][di] = __builtin_amdgcn_mfma_f32_16x16x32_bf16(pf[mi], vf[ks][di], o[mi][di], 0, 0, 0);
        }
    }

    // finalize l: reduce across quads (value for query ni*16+l16, replicated)
    #pragma unroll
    for (int ni = 0; ni < 2; ni++) {
        lsum[ni] += __shfl_xor(lsum[ni], 16, 64);
        lsum[ni] += __shfl_xor(lsum[ni], 32, 64);
    }

    // epilogue: O rows are queries (quad*4+r); fetch that row's l via shfl(width 16)
    #pragma unroll
    for (int mi = 0; mi < 2; mi++) {
        #pragma unroll
        for (int r = 0; r < 4; r++) {
            float lv = __shfl(lsum[mi], quad * 4 + r, 16);
            float inv = 1.0f / lv;
            int n = qt * 128 + wave * 32 + mi * 16 + quad * 4 + r;
            size_t base = (size_t)(b * 1024 + n) * 768 + h * 64;
            #pragma unroll
            for (int di = 0; di < 4; di++)
                ao[base + di * 16 + l16] = f2bf(o[mi][di][r] * inv);
        }
    }
}

// ---------------- output projection GEMM (+bias, fp32 out) ----------------
__global__ __launch_bounds__(256, 2) void gemm_proj(
    const u16* __restrict__ A, const u16* __restrict__ Bm,
    const float* __restrict__ bias, float* __restrict__ out)
{
    __shared__ u16 As[128][40];
    __shared__ u16 Bs[128][40];
    const int tid = threadIdx.x;
    const int wave = tid >> 6, lane = tid & 63;
    const int quad = lane >> 4, l16 = lane & 15;
    const int wr = (wave >> 1) * 64, wc = (wave & 1) * 64;
    const int rowBase = blockIdx.y * 128;
    const int colBase = blockIdx.x * 128;

    f32x4 acc[4][4] = {};

    const int r0 = tid >> 2;
    const int c0 = (tid & 3) * 8;
    const u16* ap = A + (size_t)(rowBase + r0) * 768 + c0;
    const u16* bp2 = Bm + (size_t)(colBase + r0) * 768 + c0;

    for (int k0 = 0; k0 < 768; k0 += 32) {
        __syncthreads();
        *reinterpret_cast<int4*>(&As[r0][c0])      = *reinterpret_cast<const int4*>(ap + k0);
        *reinterpret_cast<int4*>(&As[r0 + 64][c0]) = *reinterpret_cast<const int4*>(ap + 64 * 768 + k0);
        *reinterpret_cast<int4*>(&Bs[r0][c0])      = *reinterpret_cast<const int4*>(bp2 + k0);
        *reinterpret_cast<int4*>(&Bs[r0 + 64][c0]) = *reinterpret_cast<const int4*>(bp2 + 64 * 768 + k0);
        __syncthreads();
        bf16x8 a[4], b[4];
        #pragma unroll
        for (int mi = 0; mi < 4; mi++)
            a[mi] = *reinterpret_cast<const bf16x8*>(&As[wr + mi * 16 + l16][quad * 8]);
        #pragma unroll
        for (int ni = 0; ni < 4; ni++)
            b[ni] = *reinterpret_cast<const bf16x8*>(&Bs[wc + ni * 16 + l16][quad * 8]);
        #pragma unroll
        for (int mi = 0; mi < 4; mi++)
            #pragma unroll
            for (int ni = 0; ni < 4; ni++)
                acc[mi][ni] = __builtin_amdgcn_mfma_f32_16x16x32_bf16(a[mi], b[ni], acc[mi][ni], 0, 0, 0);
    }

    #pragma unroll
    for (int mi = 0; mi < 4; mi++) {
        #pragma unroll
        for (int ni = 0; ni < 4; ni++) {
            int gj = colBase + wc + ni * 16 + l16;
            float bv = bias[gj];
            int gi0 = rowBase + wr + mi * 16 + quad * 4;
            #pragma unroll
            for (int rr2 = 0; rr2 < 4; rr2++)
                out[(size_t)(gi0 + rr2) * 768 + gj] = acc[mi][ni][rr2] + bv;
        }
    }
}

extern "C" void kernel_launch(void* const* d_in, const int* in_sizes, int n_in,
                              void* d_out, int out_size, void* d_ws, size_t ws_size,
                              hipStream_t stream) {
    const float* x  = (const float*)d_in[0];
    const float* Wq = (const float*)d_in[1];
    const float* Wk = (const float*)d_in[2];
    const float* Wv = (const float*)d_in[3];
    const float* Wp = (const float*)d_in[4];
    const float* bp = (const float*)d_in[5];
    float* out = (float*)d_out;

    // workspace layout (bf16 elements); total ~64.5 MB
    u16* xb  = (u16*)d_ws;            // 6291456  : x as bf16 [8192][768]
    u16* wb  = xb  + 6291456;         // 1769472  : Wq|Wk|Wv [2304][768]
    u16* wpb = wb  + 1769472;         // 589824   : Wp [768][768]
    u16* qo  = wpb + 589824;          // 6291456  : q [B,H,N,D] (scaled)
    u16* ko  = qo  + 6291456;         // 6291456  : k [B,H,N,D]
    u16* vto = ko  + 6291456;         // 6291456  : v^T [B,H,D,N]
    u16* ao  = vto + 6291456;         // 6291456  : attn out [B,N,H*D]

    cast_f32_to_bf16<<<6144, 256, 0, stream>>>(x,  xb,  1572864);
    cast_f32_to_bf16<<<576,  256, 0, stream>>>(Wq, wb,            147456);
    cast_f32_to_bf16<<<576,  256, 0, stream>>>(Wk, wb + 589824,   147456);
    cast_f32_to_bf16<<<576,  256, 0, stream>>>(Wv, wb + 1179648,  147456);
    cast_f32_to_bf16<<<576,  256, 0, stream>>>(Wp, wpb,           147456);

    gemm_qkv<<<dim3(18, 64), 256, 0, stream>>>(xb, wb, qo, ko, vto);
    attn_fwd<<<dim3(96, 8), 256, 0, stream>>>(qo, ko, vto, ao);
    gemm_proj<<<dim3(6, 64), 256, 0, stream>>>(ao, wpb, bp, out);
}